// Round 12
// baseline (84.340 us; speedup 1.0000x reference)
//
#include <hip/hip_runtime.h>
#include <hip/hip_bf16.h>
#include <stdint.h>
#include <stddef.h>

typedef __bf16 bf16_t;
typedef __attribute__((ext_vector_type(8))) __bf16 bf16x8;
typedef __attribute__((ext_vector_type(4))) float f32x4;
typedef __attribute__((ext_vector_type(2))) float f32x2;

#define TOK 2048      // N*M tokens
#define DMODEL 1024
#define NHEAD 16

__device__ __forceinline__ void gload_lds16(const void* g, void* l) {
  __builtin_amdgcn_global_load_lds(
      (const __attribute__((address_space(1))) void*)g,
      (__attribute__((address_space(3))) void*)l, 16, 0, 0);
}

// ---------------- fp32 -> bf16 batched convert (X + weights) ----------------
struct CvtArgs {
  const float* src[7];
  bf16_t* dst[7];
  int n[7];
};

__global__ __launch_bounds__(256) void cvt_kernel(CvtArgs a) {
  int arr = blockIdx.y;
  int n = a.n[arr];
  int i = (blockIdx.x * 256 + threadIdx.x) * 8;
  if (i >= n) return;
  const float* s = a.src[arr];
  bf16_t* d = a.dst[arr];
  f32x4 x0 = *(const f32x4*)(s + i);
  f32x4 x1 = *(const f32x4*)(s + i + 4);
  bf16x8 o;
  o[0] = (bf16_t)x0[0]; o[1] = (bf16_t)x0[1]; o[2] = (bf16_t)x0[2]; o[3] = (bf16_t)x0[3];
  o[4] = (bf16_t)x1[0]; o[5] = (bf16_t)x1[1]; o[6] = (bf16_t)x1[2]; o[7] = (bf16_t)x1[3];
  *(bf16x8*)(d + i) = o;
}

// =============== deep-pipeline GEMM: 4-buf LDS, counted vmcnt, 3-step lead ===============
// C[row][col] = sum_k A[row][k]*W[col][k] + bias[col]; per z: M=2048, N=K=1024.
// 64 x (NJ*32) tile, 4 waves 2x2, BK=64, nt=16. Both operands via 16B
// global_load_lds into linear LDS, XOR chunk swizzle both sides (0 conflicts).
// Pipeline: tiles T..T+2 in flight; per step: vmcnt(8) [tile T landed, T+1/T+2
// stay out] -> s_barrier -> stage T+3 -> ds_read frags T -> MFMA. Loads get a
// 3-step (~900+cyc) lead; vmcnt NEVER drains to 0 in the main loop (T3+T4).
// Buffer recycle: stage T+3 hits buf (T-1)&3; its readers finished before the
// barrier (their ds_reads complete before MFMA of step T-1).
struct GArgs {
  const bf16_t* A[3];
  const bf16_t* W[3];
  const float* bias[3];
  void* C[3];
};

template <bool QKV3, int NJ, typename CT>
__global__ __launch_bounds__(256, 2) void gemmD(GArgs g) {
  constexpr int K = DMODEL, N = DMODEL;
  constexpr int nt = K / 64;           // 16

  // XCD-local decode (hw: blockIdx round-robins XCDs -> i&7 is the XCD)
  const int i = blockIdx.x;
  const int xcd = i & 7, slot = i >> 3;
  int z, bm, bn;
  if (QKV3) {                  // NJ=2: 1536 blocks = 8 xcd x (4 bm x 16 bn) x 3 z
    z = slot >> 6;
    const int s = slot & 63;
    bm = (xcd * 4 + (s >> 4)) * 64;
    bn = (s & 15) * 64;
  } else {                     // NJ=1: 1024 blocks = 8 xcd x (4 bm x 32 bn)
    z = 0;
    bm = (xcd * 4 + (slot >> 5)) * 64;
    bn = (slot & 31) * 32;
  }

  const bf16_t* __restrict__ A = g.A[z];
  const bf16_t* __restrict__ W = g.W[z];
  const float* __restrict__ bias = g.bias[z];
  CT* __restrict__ C = (CT*)g.C[z];

  __shared__ alignas(16) bf16_t As[4][64 * 64];        // 4 x 8 KB
  __shared__ alignas(16) bf16_t Bs[4][NJ * 32 * 64];   // 4 x (NJ*4) KB

  const int tid = threadIdx.x;
  const int wv = tid >> 6, lane = tid & 63;
  const int wr = (wv >> 1) * 32;
  const int wc = (wv & 1) * (16 * NJ);
  const int lm = lane & 15, lch = lane >> 4;
  const int cr4 = (lane >> 4) * 4;

  // staging: one gload covers 8 rows (8 lanes x 16B per row);
  // source chunk pre-XORed: LDS[r][c] = G[r][c ^ (r&7)].
  const int sr8 = lane >> 3;
  const int sc = (lane & 7) ^ sr8;
  const bf16_t* Asrc = A + (size_t)(bm + wv * 16 + sr8) * K + sc * 8;
  const bf16_t* Wsrc = W + (size_t)(bn + wv * 8 * NJ + sr8) * K + sc * 8;

  f32x4 acc[2][NJ] = {};

#define STAGE(T)                                                               \
  {                                                                            \
    const int _b = (T) & 3;                                                    \
    _Pragma("unroll") for (int j = 0; j < 2; ++j)                              \
        gload_lds16(Asrc + (size_t)(j * 8) * K + (T) * 64,                     \
                    &As[_b][(wv * 16 + j * 8) * 64]);                          \
    _Pragma("unroll") for (int j = 0; j < NJ; ++j)                             \
        gload_lds16(Wsrc + (size_t)(j * 8) * K + (T) * 64,                     \
                    &Bs[_b][(wv * 8 * NJ + j * 8) * 64]);                      \
  }

  // ---- prologue: tiles 0,1,2 in flight (12 loads/wave; 2+NJ per tile) ----
  STAGE(0);
  STAGE(1);
  STAGE(2);

  constexpr int PT = 2 + NJ;   // loads per tile per wave

#pragma unroll 1
  for (int T = 0; T < nt; ++T) {
    // counted wait: tile T landed; tiles T+1,T+2 (if staged) stay in flight
    if (T < nt - 2) {
      asm volatile("s_waitcnt vmcnt(%0) lgkmcnt(0)" ::"i"(2 * PT) : "memory");
    } else if (T == nt - 2) {
      asm volatile("s_waitcnt vmcnt(%0) lgkmcnt(0)" ::"i"(PT) : "memory");
    } else {
      asm volatile("s_waitcnt vmcnt(0) lgkmcnt(0)" ::: "memory");
    }
    __builtin_amdgcn_sched_barrier(0);
    __builtin_amdgcn_s_barrier();
    __builtin_amdgcn_sched_barrier(0);

    if (T + 3 < nt) STAGE(T + 3);
    __builtin_amdgcn_sched_barrier(0);

    const int b = T & 3;
#pragma unroll
    for (int kk = 0; kk < 2; ++kk) {
      bf16x8 fa[2], fb[NJ];
#pragma unroll
      for (int ii = 0; ii < 2; ++ii) {
        const int ra = wr + ii * 16 + lm;
        fa[ii] = *(const bf16x8*)&As[b][ra * 64 + (((kk * 4 + lch) ^ (ra & 7)) * 8)];
      }
#pragma unroll
      for (int jj = 0; jj < NJ; ++jj) {
        const int rb = wc + jj * 16 + lm;
        fb[jj] = *(const bf16x8*)&Bs[b][rb * 64 + (((kk * 4 + lch) ^ (rb & 7)) * 8)];
      }
#pragma unroll
      for (int ii = 0; ii < 2; ++ii)
#pragma unroll
        for (int jj = 0; jj < NJ; ++jj)
          acc[ii][jj] = __builtin_amdgcn_mfma_f32_16x16x32_bf16(
              fa[ii], fb[jj], acc[ii][jj], 0, 0, 0);
    }
  }
#undef STAGE

  // ---- epilogue: bias + store ----
#pragma unroll
  for (int ii = 0; ii < 2; ++ii)
#pragma unroll
    for (int jj = 0; jj < NJ; ++jj) {
      const int col = bn + wc + jj * 16 + lm;
      const float bvv = bias[col];
#pragma unroll
      for (int r = 0; r < 4; ++r) {
        const int row = bm + wr + ii * 16 + cr4 + r;
        C[(size_t)row * N + col] = (CT)(acc[ii][jj][r] + bvv);
      }
    }
}

// ---------------- per-(token,head) channel attention ----------------
// ctx[d] = sum_j exp2(a_d*k_j)*v_j / sum_j exp2(a_d*k_j); |a*k| small -> no max sub.
__global__ __launch_bounds__(256) void attn_kernel(
    const bf16_t* __restrict__ q, const bf16_t* __restrict__ k,
    const bf16_t* __restrict__ v, bf16_t* __restrict__ ctx) {
  __shared__ float kS[4][64];
  __shared__ float vS[4][64];
  const int wv = threadIdx.x >> 6, lane = threadIdx.x & 63;
  const int pair = blockIdx.x * 4 + wv;          // t*16 + h
  const size_t base = (size_t)pair * 64;
  const float sc = 0.125f * 1.44269504088896341f;  // (1/sqrt(64)) * log2(e)
  const float qd = (float)q[base + lane];
  kS[wv][lane] = (float)k[base + lane];
  vS[wv][lane] = (float)v[base + lane];
  asm volatile("s_waitcnt lgkmcnt(0)" ::: "memory");   // same-wave LDS visibility
  const float a = qd * sc;
  const f32x2 av = {a, a};
  f32x2 sum = {0.f, 0.f}, acc = {0.f, 0.f};
#pragma unroll
  for (int j = 0; j < 64; j += 4) {
    f32x4 k4 = *(const f32x4*)&kS[wv][j];
    f32x4 v4 = *(const f32x4*)&vS[wv][j];
    f32x2 t0 = av * (f32x2){k4[0], k4[1]};
    f32x2 t1 = av * (f32x2){k4[2], k4[3]};
    f32x2 e0 = {__builtin_amdgcn_exp2f(t0[0]), __builtin_amdgcn_exp2f(t0[1])};
    f32x2 e1 = {__builtin_amdgcn_exp2f(t1[0]), __builtin_amdgcn_exp2f(t1[1])};
    sum += e0 + e1;
    acc += e0 * (f32x2){v4[0], v4[1]} + e1 * (f32x2){v4[2], v4[3]};
  }
  const float s = sum[0] + sum[1];
  const float o = acc[0] + acc[1];
  ctx[base + lane] = (bf16_t)(o * __builtin_amdgcn_rcpf(s));
}

// ---------------- launch ----------------
extern "C" void kernel_launch(void* const* d_in, const int* in_sizes, int n_in,
                              void* d_out, int out_size, void* d_ws, size_t ws_size,
                              hipStream_t stream) {
  const float* query = (const float*)d_in[0];
  const float* key   = (const float*)d_in[1];
  const float* value = (const float*)d_in[2];
  const float* Wq = (const float*)d_in[3];
  const float* bq = (const float*)d_in[4];
  const float* Wk = (const float*)d_in[5];
  const float* bk = (const float*)d_in[6];
  const float* Wv = (const float*)d_in[7];
  const float* bv = (const float*)d_in[8];
  const float* Wo = (const float*)d_in[9];
  const float* bo = (const float*)d_in[10];
  float* out = (float*)d_out;

  const size_t XE = (size_t)TOK * DMODEL;
  const size_t WE = (size_t)DMODEL * DMODEL;

  char* ws = (char*)d_ws;
  size_t off = 0;
  bf16_t* xb[3];
  for (int i = 0; i < 3; ++i) { xb[i] = (bf16_t*)(ws + off); off += XE * 2; }
  bf16_t* wb[4];
  for (int i = 0; i < 4; ++i) { wb[i] = (bf16_t*)(ws + off); off += WE * 2; }
  bf16_t* pb[3];   // projected q,k,v bf16
  for (int i = 0; i < 3; ++i) { pb[i] = (bf16_t*)(ws + off); off += XE * 2; }
  bf16_t* ctxb = (bf16_t*)(ws + off); off += XE * 2;

  // 1) convert X and weights to bf16
  CvtArgs ca;
  ca.src[0] = query; ca.src[1] = key; ca.src[2] = value;
  ca.src[3] = Wq; ca.src[4] = Wk; ca.src[5] = Wv; ca.src[6] = Wo;
  ca.dst[0] = xb[0]; ca.dst[1] = xb[1]; ca.dst[2] = xb[2];
  ca.dst[3] = wb[0]; ca.dst[4] = wb[1]; ca.dst[5] = wb[2]; ca.dst[6] = wb[3];
  ca.n[0] = ca.n[1] = ca.n[2] = (int)XE;
  ca.n[3] = ca.n[4] = ca.n[5] = ca.n[6] = (int)WE;
  cvt_kernel<<<dim3((unsigned)(XE / (256 * 8)), 7), 256, 0, stream>>>(ca);

  // 2) QKV projection: 1536 blocks (64x64 tiles, 3 z's), deep pipeline
  GArgs g1;
  g1.A[0] = xb[0]; g1.A[1] = xb[1]; g1.A[2] = xb[2];
  g1.W[0] = wb[0]; g1.W[1] = wb[1]; g1.W[2] = wb[2];
  g1.bias[0] = bq; g1.bias[1] = bk; g1.bias[2] = bv;
  g1.C[0] = pb[0]; g1.C[1] = pb[1]; g1.C[2] = pb[2];
  gemmD<true, 2, bf16_t><<<dim3(1536), 256, 0, stream>>>(g1);

  // 3) per-(token,head) channel attention: 8192 blocks
  attn_kernel<<<dim3(TOK * NHEAD / 4), 256, 0, stream>>>(pb[0], pb[1], pb[2], ctxb);

  // 4) output projection -> fp32 out: 1024 blocks (64x32 tiles)
  GArgs g2;
  g2.A[0] = ctxb; g2.W[0] = wb[3]; g2.bias[0] = bo; g2.C[0] = out;
  g2.A[1] = ctxb; g2.W[1] = wb[3]; g2.bias[1] = bo; g2.C[1] = out;
  g2.A[2] = ctxb; g2.W[2] = wb[3]; g2.bias[2] = bo; g2.C[2] = out;
  gemmD<false, 1, float><<<dim3(1024), 256, 0, stream>>>(g2);
}

// Round 13
// 61.993 us; speedup vs baseline: 1.3605x; 1.3605x over previous
//
#include <hip/hip_runtime.h>
#include <hip/hip_bf16.h>
#include <stdint.h>
#include <stddef.h>

typedef __bf16 bf16_t;
typedef __attribute__((ext_vector_type(8))) __bf16 bf16x8;
typedef __attribute__((ext_vector_type(4))) float f32x4;
typedef __attribute__((ext_vector_type(2))) float f32x2;

#define TOK 2048      // N*M tokens
#define DMODEL 1024
#define NHEAD 16

__device__ __forceinline__ void gload_lds16(const void* g, void* l) {
  __builtin_amdgcn_global_load_lds(
      (const __attribute__((address_space(1))) void*)g,
      (__attribute__((address_space(3))) void*)l, 16, 0, 0);
}

// ---------------- fp32 -> bf16 batched convert (X + weights) ----------------
struct CvtArgs {
  const float* src[7];
  bf16_t* dst[7];
  int n[7];
};

__global__ __launch_bounds__(256) void cvt_kernel(CvtArgs a) {
  int arr = blockIdx.y;
  int n = a.n[arr];
  int i = (blockIdx.x * 256 + threadIdx.x) * 8;
  if (i >= n) return;
  const float* s = a.src[arr];
  bf16_t* d = a.dst[arr];
  f32x4 x0 = *(const f32x4*)(s + i);
  f32x4 x1 = *(const f32x4*)(s + i + 4);
  bf16x8 o;
  o[0] = (bf16_t)x0[0]; o[1] = (bf16_t)x0[1]; o[2] = (bf16_t)x0[2]; o[3] = (bf16_t)x0[3];
  o[4] = (bf16_t)x1[0]; o[5] = (bf16_t)x1[1]; o[6] = (bf16_t)x1[2]; o[7] = (bf16_t)x1[3];
  *(bf16x8*)(d + i) = o;
}

// =============== GEMM: (MI*32)x(NJ*32) tile, fat wave-tiles, 2-buf ===============
// C[row][col] = sum_k A[row][k]*W[col][k] + bias[col]; per z: M=2048, N=K=1024.
// 4 waves as 2x2; wave-tile = (16*MI) x (16*NJ). Bigger wave-tiles cut LDS
// read amplification (the measured bottleneck: ds_read_b128 ~85B/cyc/CU).
// Both operands staged via 16B global_load_lds into linear LDS with XOR chunk
// swizzle on BOTH global source and ds_read offsets (verified: 0 conflicts).
// One __syncthreads per K-step (R10-proven staging pattern).
struct GArgs {
  const bf16_t* A[3];
  const bf16_t* W[3];
  const float* bias[3];
  void* C[3];
};

template <bool QKV3, int MI, int NJ, typename CT>
__global__ __launch_bounds__(256, 3) void gemmS(GArgs g) {
  constexpr int K = DMODEL, N = DMODEL;
  constexpr int nt = K / 64;           // 16
  constexpr int AR = 32 * MI;          // block rows
  constexpr int BR = 32 * NJ;          // block cols

  // XCD-local decode (hw: blockIdx round-robins XCDs -> i&7 is the XCD)
  const int i = blockIdx.x;
  const int xcd = i & 7, slot = i >> 3;
  int z, bm, bn;
  if (QKV3) {                  // MI=4,NJ=2: 768 = 8 xcd x (2 bm x 16 bn) x 3 z
    z = slot >> 5;
    const int s = slot & 31;
    bm = (xcd * 2 + (s >> 4)) * AR;
    bn = (s & 15) * BR;
  } else {                     // MI=2,NJ=1: 1024 = 8 xcd x (4 bm x 32 bn)
    z = 0;
    bm = (xcd * 4 + (slot >> 5)) * AR;
    bn = (slot & 31) * BR;
  }

  const bf16_t* __restrict__ A = g.A[z];
  const bf16_t* __restrict__ W = g.W[z];
  const float* __restrict__ bias = g.bias[z];
  CT* __restrict__ C = (CT*)g.C[z];

  __shared__ alignas(16) bf16_t As[2][AR * 64];
  __shared__ alignas(16) bf16_t Bs[2][BR * 64];

  const int tid = threadIdx.x;
  const int wv = tid >> 6, lane = tid & 63;
  const int wr = (wv >> 1) * (16 * MI);
  const int wc = (wv & 1) * (16 * NJ);
  const int lm = lane & 15, lch = lane >> 4;
  const int cr4 = (lane >> 4) * 4;

  // staging: one gload covers 8 rows (8 lanes x 16B per row);
  // source chunk pre-XORed: LDS[r][c] = G[r][c ^ (r&7)].
  const int sr8 = lane >> 3;
  const int sc = (lane & 7) ^ sr8;
  const bf16_t* Asrc = A + (size_t)(bm + wv * 8 * MI + sr8) * K + sc * 8;
  const bf16_t* Wsrc = W + (size_t)(bn + wv * 8 * NJ + sr8) * K + sc * 8;

  f32x4 acc[MI][NJ] = {};

#define STAGE(T)                                                               \
  {                                                                            \
    const int _b = (T) & 1;                                                    \
    _Pragma("unroll") for (int j = 0; j < MI; ++j)                             \
        gload_lds16(Asrc + (size_t)(j * 8) * K + (T) * 64,                     \
                    &As[_b][(wv * 8 * MI + j * 8) * 64]);                      \
    _Pragma("unroll") for (int j = 0; j < NJ; ++j)                             \
        gload_lds16(Wsrc + (size_t)(j * 8) * K + (T) * 64,                     \
                    &Bs[_b][(wv * 8 * NJ + j * 8) * 64]);                      \
  }

  STAGE(0);

#pragma unroll 1
  for (int T = 0; T < nt; ++T) {
    __syncthreads();               // drains vmcnt+lgkm: tile T landed,
                                   // buf (T+1)&1 free (its readers are past)
    if (T + 1 < nt) STAGE(T + 1);
    __builtin_amdgcn_sched_barrier(0);

    const int b = T & 1;
#pragma unroll
    for (int kk = 0; kk < 2; ++kk) {
      bf16x8 fa[MI], fb[NJ];
#pragma unroll
      for (int ii = 0; ii < MI; ++ii) {
        const int ra = wr + ii * 16 + lm;
        fa[ii] = *(const bf16x8*)&As[b][ra * 64 + (((kk * 4 + lch) ^ (ra & 7)) * 8)];
      }
#pragma unroll
      for (int jj = 0; jj < NJ; ++jj) {
        const int rb = wc + jj * 16 + lm;
        fb[jj] = *(const bf16x8*)&Bs[b][rb * 64 + (((kk * 4 + lch) ^ (rb & 7)) * 8)];
      }
#pragma unroll
      for (int ii = 0; ii < MI; ++ii)
#pragma unroll
        for (int jj = 0; jj < NJ; ++jj)
          acc[ii][jj] = __builtin_amdgcn_mfma_f32_16x16x32_bf16(
              fa[ii], fb[jj], acc[ii][jj], 0, 0, 0);
    }
  }
#undef STAGE

  // ---- epilogue: bias + store ----
#pragma unroll
  for (int ii = 0; ii < MI; ++ii)
#pragma unroll
    for (int jj = 0; jj < NJ; ++jj) {
      const int col = bn + wc + jj * 16 + lm;
      const float bvv = bias[col];
#pragma unroll
      for (int r = 0; r < 4; ++r) {
        const int row = bm + wr + ii * 16 + cr4 + r;
        C[(size_t)row * N + col] = (CT)(acc[ii][jj][r] + bvv);
      }
    }
}

// ---------------- per-(token,head) channel attention ----------------
// ctx[d] = sum_j exp2(a_d*k_j)*v_j / sum_j exp2(a_d*k_j); |a*k| small -> no max sub.
__global__ __launch_bounds__(256) void attn_kernel(
    const bf16_t* __restrict__ q, const bf16_t* __restrict__ k,
    const bf16_t* __restrict__ v, bf16_t* __restrict__ ctx) {
  __shared__ float kS[4][64];
  __shared__ float vS[4][64];
  const int wv = threadIdx.x >> 6, lane = threadIdx.x & 63;
  const int pair = blockIdx.x * 4 + wv;          // t*16 + h
  const size_t base = (size_t)pair * 64;
  const float sc = 0.125f * 1.44269504088896341f;  // (1/sqrt(64)) * log2(e)
  const float qd = (float)q[base + lane];
  kS[wv][lane] = (float)k[base + lane];
  vS[wv][lane] = (float)v[base + lane];
  asm volatile("s_waitcnt lgkmcnt(0)" ::: "memory");   // same-wave LDS visibility
  const float a = qd * sc;
  const f32x2 av = {a, a};
  f32x2 sum = {0.f, 0.f}, acc = {0.f, 0.f};
#pragma unroll
  for (int j = 0; j < 64; j += 4) {
    f32x4 k4 = *(const f32x4*)&kS[wv][j];
    f32x4 v4 = *(const f32x4*)&vS[wv][j];
    f32x2 t0 = av * (f32x2){k4[0], k4[1]};
    f32x2 t1 = av * (f32x2){k4[2], k4[3]};
    f32x2 e0 = {__builtin_amdgcn_exp2f(t0[0]), __builtin_amdgcn_exp2f(t0[1])};
    f32x2 e1 = {__builtin_amdgcn_exp2f(t1[0]), __builtin_amdgcn_exp2f(t1[1])};
    sum += e0 + e1;
    acc += e0 * (f32x2){v4[0], v4[1]} + e1 * (f32x2){v4[2], v4[3]};
  }
  const float s = sum[0] + sum[1];
  const float o = acc[0] + acc[1];
  ctx[base + lane] = (bf16_t)(o * __builtin_amdgcn_rcpf(s));
}

// ---------------- launch ----------------
extern "C" void kernel_launch(void* const* d_in, const int* in_sizes, int n_in,
                              void* d_out, int out_size, void* d_ws, size_t ws_size,
                              hipStream_t stream) {
  const float* query = (const float*)d_in[0];
  const float* key   = (const float*)d_in[1];
  const float* value = (const float*)d_in[2];
  const float* Wq = (const float*)d_in[3];
  const float* bq = (const float*)d_in[4];
  const float* Wk = (const float*)d_in[5];
  const float* bk = (const float*)d_in[6];
  const float* Wv = (const float*)d_in[7];
  const float* bv = (const float*)d_in[8];
  const float* Wo = (const float*)d_in[9];
  const float* bo = (const float*)d_in[10];
  float* out = (float*)d_out;

  const size_t XE = (size_t)TOK * DMODEL;
  const size_t WE = (size_t)DMODEL * DMODEL;

  char* ws = (char*)d_ws;
  size_t off = 0;
  bf16_t* xb[3];
  for (int i = 0; i < 3; ++i) { xb[i] = (bf16_t*)(ws + off); off += XE * 2; }
  bf16_t* wb[4];
  for (int i = 0; i < 4; ++i) { wb[i] = (bf16_t*)(ws + off); off += WE * 2; }
  bf16_t* pb[3];   // projected q,k,v bf16
  for (int i = 0; i < 3; ++i) { pb[i] = (bf16_t*)(ws + off); off += XE * 2; }
  bf16_t* ctxb = (bf16_t*)(ws + off); off += XE * 2;

  // 1) convert X and weights to bf16
  CvtArgs ca;
  ca.src[0] = query; ca.src[1] = key; ca.src[2] = value;
  ca.src[3] = Wq; ca.src[4] = Wk; ca.src[5] = Wv; ca.src[6] = Wo;
  ca.dst[0] = xb[0]; ca.dst[1] = xb[1]; ca.dst[2] = xb[2];
  ca.dst[3] = wb[0]; ca.dst[4] = wb[1]; ca.dst[5] = wb[2]; ca.dst[6] = wb[3];
  ca.n[0] = ca.n[1] = ca.n[2] = (int)XE;
  ca.n[3] = ca.n[4] = ca.n[5] = ca.n[6] = (int)WE;
  cvt_kernel<<<dim3((unsigned)(XE / (256 * 8)), 7), 256, 0, stream>>>(ca);

  // 2) QKV projection: 768 blocks (128x64 tiles, wave-tile 64x32), 3/CU exact
  GArgs g1;
  g1.A[0] = xb[0]; g1.A[1] = xb[1]; g1.A[2] = xb[2];
  g1.W[0] = wb[0]; g1.W[1] = wb[1]; g1.W[2] = wb[2];
  g1.bias[0] = bq; g1.bias[1] = bk; g1.bias[2] = bv;
  g1.C[0] = pb[0]; g1.C[1] = pb[1]; g1.C[2] = pb[2];
  gemmS<true, 4, 2, bf16_t><<<dim3(768), 256, 0, stream>>>(g1);

  // 3) per-(token,head) channel attention: 8192 blocks
  attn_kernel<<<dim3(TOK * NHEAD / 4), 256, 0, stream>>>(pb[0], pb[1], pb[2], ctxb);

  // 4) output projection -> fp32 out: 1024 blocks (64x32 tiles)
  GArgs g2;
  g2.A[0] = ctxb; g2.W[0] = wb[3]; g2.bias[0] = bo; g2.C[0] = out;
  g2.A[1] = ctxb; g2.W[1] = wb[3]; g2.bias[1] = bo; g2.C[1] = out;
  g2.A[2] = ctxb; g2.W[2] = wb[3]; g2.bias[2] = bo; g2.C[2] = out;
  gemmS<false, 2, 1, float><<<dim3(1024), 256, 0, stream>>>(g2);
}